// Round 13
// baseline (3548.038 us; speedup 1.0000x reference)
//
#include <hip/hip_runtime.h>
#include <hip/hip_bf16.h>

// GRU decoder: B=64, T=512, H=1024
// Phase 0: convert W_ih/W_hh -> bf16; zero h ring + flags
// Phase 1+2 TEMPORALLY FUSED persistent scan: 128 blocks x 512 thr,
//   4 batch-groups x 32 unit-blocks (16 batches x 32 units each).
//   Per step, each wave FIRST computes its x_proj slice (enc f32 loaded+cvt
//   in-register, W_ih fragments re-read via cached loads, 24 MFMAs) -- this
//   fills the poll-wait slack -- THEN runs the round-11 proven h exchange:
//   per-wave 4-flag poll, UC h load, 24 h MFMAs, 8-slot LDS reduce
//   (r,z merged h+x pre-reduce; hn/xn separate), gates, h store->drain->
//   barrier->flag. Ring depth 4, skew<=1 proof unchanged.

typedef short bf16x8 __attribute__((ext_vector_type(8)));
typedef float f32x4 __attribute__((ext_vector_type(4)));

#define NB 64
#define NT 512
#define NH 1024
#define NG 3072           // 3*NH

static __device__ __forceinline__ float bf2f(unsigned short u) {
    unsigned int x = ((unsigned int)u) << 16;
    float f;
    __builtin_memcpy(&f, &x, sizeof(f));
    return f;
}
static __device__ __forceinline__ unsigned short f2bf(float f) {
    unsigned int x;
    __builtin_memcpy(&x, &f, sizeof(x));
    x += 0x7fffu + ((x >> 16) & 1u);  // round-to-nearest-even
    return (unsigned short)(x >> 16);
}

static __device__ __forceinline__ f32x4 mfma16(bf16x8 a, bf16x8 b, f32x4 c) {
    return __builtin_amdgcn_mfma_f32_16x16x32_bf16(a, b, c, 0, 0, 0);
}

__global__ void k_fill_sentinel(float* __restrict__ o, long n) {
    long i = (long)blockIdx.x * blockDim.x + threadIdx.x;
    if (i < n) o[i] = 12345.0f;
}

__global__ void k_convert(const float* __restrict__ in, unsigned short* __restrict__ o, int n) {
    int i = blockIdx.x * blockDim.x + threadIdx.x;
    if (i < n) o[i] = f2bf(in[i]);
}

// zero h ring (4*64*1024 bf16 = 131072 u32) + flags (128 u32)
#define SYNC_WORDS (4 * NB * NH / 2 + 128)
__global__ void k_init_sync(unsigned int* __restrict__ base) {
    int i = blockIdx.x * blockDim.x + threadIdx.x;
    if (i < SYNC_WORDS) base[i] = 0u;
}

// Fused persistent scan. Grid 128 = mg(4) x ug(32). Block 512 thr = 8 waves.
// Block owns batches m0..m0+15, units u0..u0+31 (96 Whh rows pinned in regs).
// Wave wv handles K-chunk [wv*128, +128), h produced by ublocks wv*4..wv*4+3.
__global__ __launch_bounds__(512, 1) void k_scan(
    const unsigned short* __restrict__ Wih,   // [3H, H] bf16
    const unsigned short* __restrict__ Whh,   // [3H, H] bf16
    const float* __restrict__ bih,            // [3H]
    const float* __restrict__ bhh,            // [3H]
    const float* __restrict__ enc,            // [B, T, H] f32
    unsigned short* __restrict__ hring,       // [4][64][1024] bf16
    unsigned* __restrict__ flags,             // [128] = [mg*32+ug]
    float* __restrict__ out)                  // [B, T, H] f32
{
    const int tid  = threadIdx.x;
    const int lane = tid & 63;
    const int wv   = tid >> 6;        // 0..7
    const int l16  = lane & 15;
    const int lq   = lane >> 4;
    const int bid  = blockIdx.x;
    const int mg   = bid >> 5;        // 0..3
    const int ug   = bid & 31;        // 0..31
    const int m0   = mg * 16;
    const int u0   = ug * 32;
    const int kc0  = wv * 128;

    // Whh slice as MFMA B-fragments, pinned for the whole scan.
    bf16x8 Bf[3][2][4];
#pragma unroll
    for (int g = 0; g < 3; ++g)
#pragma unroll
        for (int f = 0; f < 2; ++f)
#pragma unroll
            for (int ks = 0; ks < 4; ++ks)
                Bf[g][f][ks] = *(const bf16x8*)(Whh + (long)(g * NH + u0 + f * 16 + l16) * NH + kc0 + ks * 32 + lq * 8);
#pragma unroll
    for (int g = 0; g < 3; ++g)
#pragma unroll
        for (int f = 0; f < 2; ++f)
#pragma unroll
            for (int ks = 0; ks < 4; ++ks)
                asm volatile("" : "+v"(Bf[g][f][ks]));  // forbid rematerialization

    // epilogue ownership: 1 output (b_own, u_own) per thread
    const int u_loc = tid & 31;
    const int b_loc = tid >> 5;       // 0..15
    const int b_own = m0 + b_loc;
    const int u_own = u0 + u_loc;
    float bi[3], bh[3];
#pragma unroll
    for (int g = 0; g < 3; ++g) { bi[g] = bih[g * NH + u_own]; bh[g] = bhh[g * NH + u_own]; }
    float hf = 0.0f;                  // fp32 h for (b_own,u_own), in-register

    // C-frag element holding (b_loc, u_loc&15)
    const int lane_t = (b_loc >> 2) * 16 + (u_loc & 15);
    const int i_t    = b_loc & 3;
    const int shalf  = (u_loc >> 4) * 4;   // frag-slot base: 0 or 4

    // this wave's 4 h-producer flags
    const unsigned* fp_my = flags + mg * 32 + wv * 4 + (lane & 3);

    // per-lane base pointers (A-row = m0+l16, k = kc0+lq*8)
    const float* enc_base = enc + ((size_t)(m0 + l16) * NT) * NH + kc0 + lq * 8;
    const unsigned short* wih_base = Wih + (size_t)(u0 + l16) * NH + kc0 + lq * 8;

    __shared__ f32x4 red[8][8][64];   // 64 KB

    for (int t = 0; t < NT; ++t) {
        const int slot_r = (t + 3) & 3;
        const int slot_w = t & 3;

        // ====== x_proj slice (independent of flags; fills poll slack) ======
        f32x4 accx[2][3];
#pragma unroll
        for (int f = 0; f < 2; ++f)
#pragma unroll
            for (int g = 0; g < 3; ++g) accx[f][g] = (f32x4){0.f, 0.f, 0.f, 0.f};

        const float* ep = enc_base + (size_t)t * NH;
#pragma unroll
        for (int ks = 0; ks < 4; ++ks) {
            float4 fa = *(const float4*)(ep + ks * 32);
            float4 fb = *(const float4*)(ep + ks * 32 + 4);
            union { unsigned short s[8]; bf16x8 v; } cv;
            cv.s[0] = f2bf(fa.x); cv.s[1] = f2bf(fa.y);
            cv.s[2] = f2bf(fa.z); cv.s[3] = f2bf(fa.w);
            cv.s[4] = f2bf(fb.x); cv.s[5] = f2bf(fb.y);
            cv.s[6] = f2bf(fb.z); cv.s[7] = f2bf(fb.w);
            bf16x8 avx = cv.v;
#pragma unroll
            for (int g = 0; g < 3; ++g)
#pragma unroll
                for (int f = 0; f < 2; ++f) {
                    bf16x8 bx = *(const bf16x8*)(wih_base + ((size_t)g * NH + f * 16) * NH + ks * 32);
                    accx[f][g] = mfma16(avx, bx, accx[f][g]);
                }
        }

        // ====== per-wave poll: this wave's 4 h-producers ======
        if (t > 0) {
            for (;;) {
                unsigned fv;
                asm volatile("global_load_dword %0, %1, off sc0 sc1\n\ts_waitcnt vmcnt(0)"
                             : "=v"(fv) : "v"(fp_my) : "memory");
                if (__all(fv >= (unsigned)t)) break;
            }
        }

        // ====== h chunk load (UC), exactly once: 4 x dwordx4 ======
        const unsigned short* hp = hring + ((slot_r * NB + m0 + l16) * NH + kc0 + lq * 8);
        bf16x8 av[4];
        asm volatile(
            "global_load_dwordx4 %0, %4, off sc0 sc1\n\t"
            "global_load_dwordx4 %1, %4, off offset:64 sc0 sc1\n\t"
            "global_load_dwordx4 %2, %4, off offset:128 sc0 sc1\n\t"
            "global_load_dwordx4 %3, %4, off offset:192 sc0 sc1\n\t"
            "s_waitcnt vmcnt(0)"
            : "=&v"(av[0]), "=&v"(av[1]), "=&v"(av[2]), "=&v"(av[3])
            : "v"(hp) : "memory");

        f32x4 acch[2][3];
#pragma unroll
        for (int f = 0; f < 2; ++f)
#pragma unroll
            for (int g = 0; g < 3; ++g) acch[f][g] = (f32x4){0.f, 0.f, 0.f, 0.f};
#pragma unroll
        for (int ks = 0; ks < 4; ++ks)
#pragma unroll
            for (int f = 0; f < 2; ++f)
#pragma unroll
                for (int g = 0; g < 3; ++g)
                    acch[f][g] = mfma16(av[ks], Bf[g][f][ks], acch[f][g]);

        // ====== 8-slot reduce: r,z merged (h+x); hn, xn separate ======
#pragma unroll
        for (int f = 0; f < 2; ++f) {
            red[wv][f * 4 + 0][lane] = acch[f][0] + accx[f][0];
            red[wv][f * 4 + 1][lane] = acch[f][1] + accx[f][1];
            red[wv][f * 4 + 2][lane] = acch[f][2];
            red[wv][f * 4 + 3][lane] = accx[f][2];
        }
        __syncthreads();  // all waves' partials in LDS (union of polls = 32 blocks >= t)

        float s_r = 0.f, s_z = 0.f, s_hn = 0.f, s_xn = 0.f;
#pragma unroll
        for (int w = 0; w < 8; ++w) {
            s_r  += red[w][shalf + 0][lane_t][i_t];
            s_z  += red[w][shalf + 1][lane_t][i_t];
            s_hn += red[w][shalf + 2][lane_t][i_t];
            s_xn += red[w][shalf + 3][lane_t][i_t];
        }

        float r = 1.0f / (1.0f + __expf(-(s_r + bi[0] + bh[0])));
        float z = 1.0f / (1.0f + __expf(-(s_z + bi[1] + bh[1])));
        float narg = (s_xn + bi[2]) + r * (s_hn + bh[2]);
        float nval = 1.0f - 2.0f / (__expf(2.0f * narg) + 1.0f);  // tanh
        float hnew = (1.0f - z) * nval + z * hf;
        hf = hnew;

        // h store (sc0 sc1) -> drain -> barrier (also guards red[]) -> flag
        {
            unsigned short* hw = hring + (slot_w * NB + b_own) * NH + u_own;
            unsigned hv = (unsigned)f2bf(hnew);
            asm volatile("global_store_short %0, %1, off sc0 sc1"
                         :: "v"(hw), "v"(hv) : "memory");
        }
        asm volatile("s_waitcnt vmcnt(0)" ::: "memory");  // h visible at coherent point
        __syncthreads();                                   // all waves drained + red[] free
        if (tid == 0) {
            unsigned fv = (unsigned)(t + 1);
            asm volatile("global_store_dword %0, %1, off sc0 sc1"
                         :: "v"(flags + mg * 32 + ug), "v"(fv) : "memory");
        }
        out[((long)b_own * NT + t) * NH + u_own] = hnew;
    }
}

extern "C" void kernel_launch(void* const* d_in, const int* in_sizes, int n_in,
                              void* d_out, int out_size, void* d_ws, size_t ws_size,
                              hipStream_t stream) {
    const float* enc = (const float*)d_in[0];
    const float* Wih = (const float*)d_in[1];
    const float* Whh = (const float*)d_in[2];
    const float* bih = (const float*)d_in[3];
    const float* bhh = (const float*)d_in[4];
    float* out = (float*)d_out;

    // workspace carve (small now: no enc_t, no xp)
    char* p = (char*)d_ws;
    unsigned short* wih_b = (unsigned short*)p; p += (size_t)NG * NH * 2;        // 6 MB
    unsigned short* whh_b = (unsigned short*)p; p += (size_t)NG * NH * 2;        // 6 MB
    unsigned short* hring = (unsigned short*)p; p += (size_t)4 * NB * NH * 2;    // 512 KB
    unsigned* flags = (unsigned*)p; p += 128 * 4;
    size_t need = (size_t)(p - (char*)d_ws);

    if (ws_size < need) {
        long n = (long)out_size;
        k_fill_sentinel<<<(int)((n + 255) / 256), 256, 0, stream>>>(out, n);
        return;
    }

    // Phase 0: weight conversions + sync init
    {
        int n = NG * NH;  // 3145728
        k_convert<<<(n + 255) / 256, 256, 0, stream>>>(Wih, wih_b, n);
        k_convert<<<(n + 255) / 256, 256, 0, stream>>>(Whh, whh_b, n);
        k_init_sync<<<(SYNC_WORDS + 255) / 256, 256, 0, stream>>>((unsigned*)hring);
    }

    // Fused persistent scan (x_proj computed in-step, in poll slack)
    k_scan<<<128, 512, 0, stream>>>(wih_b, whh_b, bih, bhh, enc,
                                    hring, flags, out);
}

// Round 14
// 2612.675 us; speedup vs baseline: 1.3580x; 1.3580x over previous
//
#include <hip/hip_runtime.h>
#include <hip/hip_bf16.h>

// GRU decoder: B=64, T=512, H=1024
// Phase 0: k_prep — enc -> bf16 [T,B,H] + W_ih/W_hh -> bf16 (one kernel)
// Phase 1: x_proj GEMM, m97-style 128x128 tile, XCD-swizzled 1D grid
// Phase 1.5: zero h ring + per-wave flags (aliases dead enc_t region)
// Phase 2: persistent scan, 128 blocks x 512 thr, 4 batch-groups x 32 unit-blocks.
//   Round-11 protocol + EARLY PER-WAVE FLAGS: each producer wave publishes its
//   own flag right after its own vmcnt(0) drain (before the red[] barrier), so
//   the block's slowest wave is off the inter-block visibility chain. Consumer
//   wave polls its 4 producer blocks x 8 waves = 32 flags (1 dword/lane).
//   Ring depth 4, skew<=1 proof unchanged.

typedef short bf16x8 __attribute__((ext_vector_type(8)));
typedef float f32x4 __attribute__((ext_vector_type(4)));

#define NB 64
#define NT 512
#define NH 1024
#define NG 3072           // 3*NH

static __device__ __forceinline__ float bf2f(unsigned short u) {
    unsigned int x = ((unsigned int)u) << 16;
    float f;
    __builtin_memcpy(&f, &x, sizeof(f));
    return f;
}
static __device__ __forceinline__ unsigned short f2bf(float f) {
    unsigned int x;
    __builtin_memcpy(&x, &f, sizeof(x));
    x += 0x7fffu + ((x >> 16) & 1u);  // round-to-nearest-even
    return (unsigned short)(x >> 16);
}

static __device__ __forceinline__ f32x4 mfma16(bf16x8 a, bf16x8 b, f32x4 c) {
    return __builtin_amdgcn_mfma_f32_16x16x32_bf16(a, b, c, 0, 0, 0);
}

// async global->LDS, 16B per lane; LDS dest = wave-uniform base + lane*16
#define GLD16(gp, lp) __builtin_amdgcn_global_load_lds( \
    (const __attribute__((address_space(1))) void*)(gp), \
    (__attribute__((address_space(3))) void*)(lp), 16, 0, 0)

__global__ void k_fill_sentinel(float* __restrict__ o, long n) {
    long i = (long)blockIdx.x * blockDim.x + threadIdx.x;
    if (i < n) o[i] = 12345.0f;
}

// enc [B,T,H] f32 -> enc_t [T,B,H] bf16; also converts both weight matrices.
__global__ void k_prep(const float* __restrict__ enc, unsigned short* __restrict__ enc_t,
                       const float* __restrict__ Wih, unsigned short* __restrict__ wih_b,
                       const float* __restrict__ Whh, unsigned short* __restrict__ whh_b) {
    long i = (long)blockIdx.x * blockDim.x + threadIdx.x;
    if (i < (long)NB * NT * NH) {
        int h = (int)(i % NH);
        long bt = i / NH;
        int t = (int)(bt % NT);
        int b = (int)(bt / NT);
        enc_t[((long)t * NB + b) * NH + h] = f2bf(enc[i]);
    }
    if (i < (long)NG * NH) {
        wih_b[i] = f2bf(Wih[i]);
        whh_b[i] = f2bf(Whh[i]);
    }
}

// zero h ring (4*64*1024 bf16 = 131072 u32) + per-wave flags (1024 u32)
#define SYNC_WORDS (4 * NB * NH / 2 + 1024)
__global__ void k_init_sync(unsigned int* __restrict__ base) {
    int i = blockIdx.x * blockDim.x + threadIdx.x;
    if (i < SYNC_WORDS) base[i] = 0u;
}

// Phase 1 GEMM, m97 structure, 1D grid with XCD swizzle.
// M = T*B = 32768, N = 3072, K = 1024. 6144 blocks, 256 thr.
__global__ __launch_bounds__(256) void k_xproj(
    const unsigned short* __restrict__ X,   // [M, K] bf16
    const unsigned short* __restrict__ W,   // [N, K] bf16
    const float* __restrict__ bias,         // [N]
    unsigned short* __restrict__ xp)        // [T][32][64][96] bf16
{
    __shared__ unsigned short As[128 * 32];
    __shared__ unsigned short Bs[128 * 32];

    const int tid  = threadIdx.x;
    const int lane = tid & 63;
    const int wv   = tid >> 6;
    const int l16  = lane & 15;
    const int lq   = lane >> 4;
    const int wr   = wv >> 1;
    const int wc   = wv & 1;
    // XCD swizzle: 6144 % 8 == 0 -> each XCD gets 768 consecutive swz
    const int bid  = blockIdx.x;
    const int swz  = (bid & 7) * 768 + (bid >> 3);
    const int n0   = (swz % 24) * 128;
    const int m0   = (swz / 24) * 128;

    f32x4 acc[4][4];
#pragma unroll
    for (int mi = 0; mi < 4; ++mi)
#pragma unroll
        for (int nj = 0; nj < 4; ++nj) acc[mi][nj] = (f32x4){0.f, 0.f, 0.f, 0.f};

    const int r0 = tid >> 2;
    const int c0e = (tid & 3) * 8;
    const int r1 = (256 + tid) >> 2;

    for (int k0 = 0; k0 < NH; k0 += 32) {
        GLD16(X + (size_t)(m0 + r0) * NH + k0 + c0e, &As[tid * 8]);
        GLD16(X + (size_t)(m0 + r1) * NH + k0 + c0e, &As[(256 + tid) * 8]);
        GLD16(W + (size_t)(n0 + r0) * NH + k0 + c0e, &Bs[tid * 8]);
        GLD16(W + (size_t)(n0 + r1) * NH + k0 + c0e, &Bs[(256 + tid) * 8]);
        __syncthreads();

        bf16x8 a[4], b[4];
#pragma unroll
        for (int mi = 0; mi < 4; ++mi)
            a[mi] = *(const bf16x8*)&As[(wr * 64 + mi * 16 + l16) * 32 + lq * 8];
#pragma unroll
        for (int nj = 0; nj < 4; ++nj)
            b[nj] = *(const bf16x8*)&Bs[(wc * 64 + nj * 16 + l16) * 32 + lq * 8];
#pragma unroll
        for (int mi = 0; mi < 4; ++mi)
#pragma unroll
            for (int nj = 0; nj < 4; ++nj)
                acc[mi][nj] = mfma16(a[mi], b[nj], acc[mi][nj]);
        __syncthreads();
    }

#pragma unroll
    for (int nj = 0; nj < 4; ++nj) {
        int n = n0 + wc * 64 + nj * 16 + l16;
        float bv = bias[n];
        int g   = n >> 10;
        int u   = n & 1023;
        int ugb = u >> 5;
        int ui  = u & 31;
#pragma unroll
        for (int mi = 0; mi < 4; ++mi) {
#pragma unroll
            for (int i = 0; i < 4; ++i) {
                int m = m0 + wr * 64 + mi * 16 + lq * 4 + i;
                int t = m >> 6;
                int b = m & 63;
                xp[(((long)t * 32 + ugb) * 64 + b) * 96 + g * 32 + ui] = f2bf(acc[mi][nj][i] + bv);
            }
        }
    }
}

// Phase 2: persistent scan, per-wave early-flag protocol.
// Grid 128 = mg(4) x ug(32). Block 512 thr = 8 waves.
// Block owns batches m0..m0+15, units u0..u0+31 (96 Whh rows in regs).
// Wave wv handles K-chunk [wv*128, +128), produced by ublocks wv*4..wv*4+3.
// flags[mg*256 + ug*8 + w] = steps completed (and drained) by wave w of block ug.
__global__ __launch_bounds__(512, 1) void k_scan(
    const unsigned short* __restrict__ Whh,   // [3H, H] bf16
    const float* __restrict__ bhh,            // [3H]
    const unsigned short* __restrict__ xp,    // [T][32][64][96] bf16
    unsigned short* __restrict__ hring,       // [4][64][1024] bf16
    unsigned* __restrict__ flags,             // [4][32][8]
    float* __restrict__ out)                  // [B, T, H] f32
{
    const int tid  = threadIdx.x;
    const int lane = tid & 63;
    const int wv   = tid >> 6;        // 0..7
    const int l16  = lane & 15;
    const int lq   = lane >> 4;
    const int bid  = blockIdx.x;
    const int mg   = bid >> 5;        // 0..3
    const int ug   = bid & 31;        // 0..31
    const int m0   = mg * 16;
    const int u0   = ug * 32;
    const int kc0  = wv * 128;

    // Whh slice as MFMA B-fragments, pinned for the whole scan.
    bf16x8 Bf[3][2][4];
#pragma unroll
    for (int g = 0; g < 3; ++g)
#pragma unroll
        for (int f = 0; f < 2; ++f)
#pragma unroll
            for (int ks = 0; ks < 4; ++ks)
                Bf[g][f][ks] = *(const bf16x8*)(Whh + (long)(g * NH + u0 + f * 16 + l16) * NH + kc0 + ks * 32 + lq * 8);
#pragma unroll
    for (int g = 0; g < 3; ++g)
#pragma unroll
        for (int f = 0; f < 2; ++f)
#pragma unroll
            for (int ks = 0; ks < 4; ++ks)
                asm volatile("" : "+v"(Bf[g][f][ks]));  // forbid rematerialization

    // epilogue ownership: 1 output (b_own, u_own) per thread
    const int u_loc = tid & 31;
    const int b_loc = tid >> 5;       // 0..15
    const int b_own = m0 + b_loc;
    const int u_own = u0 + u_loc;
    float bh[3];
#pragma unroll
    for (int g = 0; g < 3; ++g) bh[g] = bhh[g * NH + u_own];
    float hf = 0.0f;                  // fp32 h for (b_own,u_own), in-register

    // C-frag element holding (b_loc, u_loc&15)
    const int lane_t = (b_loc >> 2) * 16 + (u_loc & 15);
    const int i_t    = b_loc & 3;
    const int shalf  = (u_loc >> 4) * 3;   // frag-slot base: 0 or 3

    // this wave's 32 producer-wave flags: blocks wv*4 + (lane&31)>>3, wave lane&7
    const unsigned* fp_my = flags + mg * 256 + (wv * 4 + ((lane & 31) >> 3)) * 8 + (lane & 7);
    // this wave's own flag slot
    unsigned* fp_own = flags + mg * 256 + ug * 8 + wv;

    __shared__ f32x4 red[8][6][64];   // 48 KB

    for (int t = 0; t < NT; ++t) {
        const int slot_r = (t + 3) & 3;
        const int slot_w = t & 3;

        // xp loads for epilogue (plain cached; overlap with the poll)
        const unsigned short* xpp = xp + (((long)t * 32 + ug) * 64 + b_own) * 96;
        float xr = bf2f(xpp[u_loc]);
        float xz = bf2f(xpp[32 + u_loc]);
        float xn = bf2f(xpp[64 + u_loc]);

        // ---- per-wave poll: this wave's 4 producer blocks x 8 waves ----
        if (t > 0) {
            for (;;) {
                unsigned fv;
                asm volatile("global_load_dword %0, %1, off sc0 sc1\n\ts_waitcnt vmcnt(0)"
                             : "=v"(fv) : "v"(fp_my) : "memory");
                if (__all(fv >= (unsigned)t)) break;
            }
        }

        // ---- h chunk load, exactly once: 4 x dwordx4 = 64B/lane ----
        const unsigned short* hp = hring + ((slot_r * NB + m0 + l16) * NH + kc0 + lq * 8);
        bf16x8 av[4];
        asm volatile(
            "global_load_dwordx4 %0, %4, off sc0 sc1\n\t"
            "global_load_dwordx4 %1, %4, off offset:64 sc0 sc1\n\t"
            "global_load_dwordx4 %2, %4, off offset:128 sc0 sc1\n\t"
            "global_load_dwordx4 %3, %4, off offset:192 sc0 sc1\n\t"
            "s_waitcnt vmcnt(0)"
            : "=&v"(av[0]), "=&v"(av[1]), "=&v"(av[2]), "=&v"(av[3])
            : "v"(hp) : "memory");

        f32x4 acc[2][3];
#pragma unroll
        for (int f = 0; f < 2; ++f)
#pragma unroll
            for (int g = 0; g < 3; ++g) acc[f][g] = (f32x4){0.f, 0.f, 0.f, 0.f};
#pragma unroll
        for (int ks = 0; ks < 4; ++ks)
#pragma unroll
            for (int f = 0; f < 2; ++f)
#pragma unroll
                for (int g = 0; g < 3; ++g)
                    acc[f][g] = mfma16(av[ks], Bf[g][f][ks], acc[f][g]);

#pragma unroll
        for (int f = 0; f < 2; ++f)
#pragma unroll
            for (int g = 0; g < 3; ++g) red[wv][f * 3 + g][lane] = acc[f][g];
        __syncthreads();  // all waves' partials in LDS (union of polls = 32 blocks >= t)

        float pre[3];
#pragma unroll
        for (int g = 0; g < 3; ++g) {
            float s = 0.0f;
#pragma unroll
            for (int w = 0; w < 8; ++w) s += red[w][shalf + g][lane_t][i_t];
            pre[g] = s + bh[g];
        }

        float r = 1.0f / (1.0f + __expf(-(xr + pre[0])));
        float z = 1.0f / (1.0f + __expf(-(xz + pre[1])));
        float narg = xn + r * pre[2];
        float nval = 1.0f - 2.0f / (__expf(2.0f * narg) + 1.0f);  // tanh
        float hnew = (1.0f - z) * nval + z * hf;
        hf = hnew;

        // h store -> per-wave drain -> EARLY per-wave flag -> barrier (red[] guard)
        {
            unsigned short* hw = hring + (slot_w * NB + b_own) * NH + u_own;
            unsigned hv = (unsigned)f2bf(hnew);
            asm volatile("global_store_short %0, %1, off sc0 sc1"
                         :: "v"(hw), "v"(hv) : "memory");
        }
        asm volatile("s_waitcnt vmcnt(0)" ::: "memory");  // this wave's h visible
        if (lane == 0) {
            unsigned fv = (unsigned)(t + 1);
            asm volatile("global_store_dword %0, %1, off sc0 sc1"
                         :: "v"(fp_own), "v"(fv) : "memory");
        }
        out[((long)b_own * NT + t) * NH + u_own] = hnew;
        __syncthreads();  // red[] free for next iteration
    }
}

extern "C" void kernel_launch(void* const* d_in, const int* in_sizes, int n_in,
                              void* d_out, int out_size, void* d_ws, size_t ws_size,
                              hipStream_t stream) {
    const float* enc = (const float*)d_in[0];
    const float* Wih = (const float*)d_in[1];
    const float* Whh = (const float*)d_in[2];
    const float* bih = (const float*)d_in[3];
    const float* bhh = (const float*)d_in[4];
    float* out = (float*)d_out;

    // workspace carve
    char* p = (char*)d_ws;
    unsigned short* enc_t = (unsigned short*)p; p += (size_t)NT * NB * NH * 2;   // 64 MB
    unsigned short* xp    = (unsigned short*)p; p += (size_t)NT * NB * NG * 2;   // 192 MB
    unsigned short* wih_b = (unsigned short*)p; p += (size_t)NG * NH * 2;        // 6 MB
    unsigned short* whh_b = (unsigned short*)p; p += (size_t)NG * NH * 2;        // 6 MB
    size_t need = (size_t)(p - (char*)d_ws);

    // sync region aliases dead enc_t: [hring 4*64*1024 bf16][flags 1024 u32]
    unsigned short* hring = enc_t;
    unsigned* flags = (unsigned*)(hring + (size_t)4 * NB * NH);

    if (ws_size < need) {
        long n = (long)out_size;
        k_fill_sentinel<<<(int)((n + 255) / 256), 256, 0, stream>>>(out, n);
        return;
    }

    // Phase 0: conversions (one kernel)
    {
        long ne = (long)NB * NT * NH;  // 33554432, covers NG*NH too
        k_prep<<<(int)((ne + 255) / 256), 256, 0, stream>>>(enc, enc_t, Wih, wih_b, Whh, whh_b);
    }

    // Phase 1: x_proj GEMM (reads enc_t), XCD-swizzled 1D grid
    k_xproj<<<6144, 256, 0, stream>>>(enc_t, wih_b, bih, xp);

    // Phase 1.5: zero sync region (after enc_t is dead)
    k_init_sync<<<(SYNC_WORDS + 255) / 256, 256, 0, stream>>>((unsigned*)hring);

    // Phase 2: one persistent scan kernel
    k_scan<<<128, 512, 0, stream>>>(whh_b, bhh, xp, hring, flags, out);
}

// Round 15
// 2282.100 us; speedup vs baseline: 1.5547x; 1.1449x over previous
//
#include <hip/hip_runtime.h>
#include <hip/hip_bf16.h>

// GRU decoder: B=64, T=512, H=1024
// Phase 0: k_prep — enc -> bf16 [T,B,H] + W_ih/W_hh -> bf16 (one kernel)
// Phase 1: x_proj GEMM, m97-style 128x128 tile, XCD-swizzled 1D grid
// Phase 1.5: zero h ring + flags (aliases dead enc_t region)
// Phase 2: persistent scan — ROUND-11 VERIFIED PROTOCOL VERBATIM:
//   128 blocks x 512 thr, 4 batch-groups x 32 unit-blocks, Whh pinned in regs,
//   per-wave 4-flag poll, single UC h load, h store -> vmcnt(0) -> barrier ->
//   tid0 block flag. Ring depth 4, skew<=1.

typedef short bf16x8 __attribute__((ext_vector_type(8)));
typedef float f32x4 __attribute__((ext_vector_type(4)));

#define NB 64
#define NT 512
#define NH 1024
#define NG 3072           // 3*NH

static __device__ __forceinline__ float bf2f(unsigned short u) {
    unsigned int x = ((unsigned int)u) << 16;
    float f;
    __builtin_memcpy(&f, &x, sizeof(f));
    return f;
}
static __device__ __forceinline__ unsigned short f2bf(float f) {
    unsigned int x;
    __builtin_memcpy(&x, &f, sizeof(x));
    x += 0x7fffu + ((x >> 16) & 1u);  // round-to-nearest-even
    return (unsigned short)(x >> 16);
}

static __device__ __forceinline__ f32x4 mfma16(bf16x8 a, bf16x8 b, f32x4 c) {
    return __builtin_amdgcn_mfma_f32_16x16x32_bf16(a, b, c, 0, 0, 0);
}

// async global->LDS, 16B per lane; LDS dest = wave-uniform base + lane*16
#define GLD16(gp, lp) __builtin_amdgcn_global_load_lds( \
    (const __attribute__((address_space(1))) void*)(gp), \
    (__attribute__((address_space(3))) void*)(lp), 16, 0, 0)

__global__ void k_fill_sentinel(float* __restrict__ o, long n) {
    long i = (long)blockIdx.x * blockDim.x + threadIdx.x;
    if (i < n) o[i] = 12345.0f;
}

// enc [B,T,H] f32 -> enc_t [T,B,H] bf16; also converts both weight matrices.
__global__ void k_prep(const float* __restrict__ enc, unsigned short* __restrict__ enc_t,
                       const float* __restrict__ Wih, unsigned short* __restrict__ wih_b,
                       const float* __restrict__ Whh, unsigned short* __restrict__ whh_b) {
    long i = (long)blockIdx.x * blockDim.x + threadIdx.x;
    if (i < (long)NB * NT * NH) {
        int h = (int)(i % NH);
        long bt = i / NH;
        int t = (int)(bt % NT);
        int b = (int)(bt / NT);
        enc_t[((long)t * NB + b) * NH + h] = f2bf(enc[i]);
    }
    if (i < (long)NG * NH) {
        wih_b[i] = f2bf(Wih[i]);
        whh_b[i] = f2bf(Whh[i]);
    }
}

// zero h ring (4*64*1024 bf16 = 131072 u32) + flags (128 u32)
#define SYNC_WORDS (4 * NB * NH / 2 + 128)
__global__ void k_init_sync(unsigned int* __restrict__ base) {
    int i = blockIdx.x * blockDim.x + threadIdx.x;
    if (i < SYNC_WORDS) base[i] = 0u;
}

// Phase 1 GEMM, m97 structure, 1D grid with XCD swizzle.
// M = T*B = 32768, N = 3072, K = 1024. 6144 blocks, 256 thr.
__global__ __launch_bounds__(256) void k_xproj(
    const unsigned short* __restrict__ X,   // [M, K] bf16
    const unsigned short* __restrict__ W,   // [N, K] bf16
    const float* __restrict__ bias,         // [N]
    unsigned short* __restrict__ xp)        // [T][32][64][96] bf16
{
    __shared__ unsigned short As[128 * 32];
    __shared__ unsigned short Bs[128 * 32];

    const int tid  = threadIdx.x;
    const int lane = tid & 63;
    const int wv   = tid >> 6;
    const int l16  = lane & 15;
    const int lq   = lane >> 4;
    const int wr   = wv >> 1;
    const int wc   = wv & 1;
    // XCD swizzle: 6144 % 8 == 0 -> each XCD gets 768 consecutive swz
    const int bid  = blockIdx.x;
    const int swz  = (bid & 7) * 768 + (bid >> 3);
    const int n0   = (swz % 24) * 128;
    const int m0   = (swz / 24) * 128;

    f32x4 acc[4][4];
#pragma unroll
    for (int mi = 0; mi < 4; ++mi)
#pragma unroll
        for (int nj = 0; nj < 4; ++nj) acc[mi][nj] = (f32x4){0.f, 0.f, 0.f, 0.f};

    const int r0 = tid >> 2;
    const int c0e = (tid & 3) * 8;
    const int r1 = (256 + tid) >> 2;

    for (int k0 = 0; k0 < NH; k0 += 32) {
        GLD16(X + (size_t)(m0 + r0) * NH + k0 + c0e, &As[tid * 8]);
        GLD16(X + (size_t)(m0 + r1) * NH + k0 + c0e, &As[(256 + tid) * 8]);
        GLD16(W + (size_t)(n0 + r0) * NH + k0 + c0e, &Bs[tid * 8]);
        GLD16(W + (size_t)(n0 + r1) * NH + k0 + c0e, &Bs[(256 + tid) * 8]);
        __syncthreads();

        bf16x8 a[4], b[4];
#pragma unroll
        for (int mi = 0; mi < 4; ++mi)
            a[mi] = *(const bf16x8*)&As[(wr * 64 + mi * 16 + l16) * 32 + lq * 8];
#pragma unroll
        for (int nj = 0; nj < 4; ++nj)
            b[nj] = *(const bf16x8*)&Bs[(wc * 64 + nj * 16 + l16) * 32 + lq * 8];
#pragma unroll
        for (int mi = 0; mi < 4; ++mi)
#pragma unroll
            for (int nj = 0; nj < 4; ++nj)
                acc[mi][nj] = mfma16(a[mi], b[nj], acc[mi][nj]);
        __syncthreads();
    }

#pragma unroll
    for (int nj = 0; nj < 4; ++nj) {
        int n = n0 + wc * 64 + nj * 16 + l16;
        float bv = bias[n];
        int g   = n >> 10;
        int u   = n & 1023;
        int ugb = u >> 5;
        int ui  = u & 31;
#pragma unroll
        for (int mi = 0; mi < 4; ++mi) {
#pragma unroll
            for (int i = 0; i < 4; ++i) {
                int m = m0 + wr * 64 + mi * 16 + lq * 4 + i;
                int t = m >> 6;
                int b = m & 63;
                xp[(((long)t * 32 + ugb) * 64 + b) * 96 + g * 32 + ui] = f2bf(acc[mi][nj][i] + bv);
            }
        }
    }
}

// Phase 2: persistent scan — round-11 verified protocol.
// Grid 128 = mg(4) x ug(32). Block 512 thr = 8 waves.
// Block owns batches m0..m0+15, units u0..u0+31 (96 Whh rows pinned in regs).
// Wave wv handles K-chunk [wv*128, +128), produced by ublocks wv*4..wv*4+3.
__global__ __launch_bounds__(512, 1) void k_scan(
    const unsigned short* __restrict__ Whh,   // [3H, H] bf16
    const float* __restrict__ bhh,            // [3H]
    const unsigned short* __restrict__ xp,    // [T][32][64][96] bf16
    unsigned short* __restrict__ hring,       // [4][64][1024] bf16
    unsigned* __restrict__ flags,             // [128] = [mg*32+ug]
    float* __restrict__ out)                  // [B, T, H] f32
{
    const int tid  = threadIdx.x;
    const int lane = tid & 63;
    const int wv   = tid >> 6;        // 0..7
    const int l16  = lane & 15;
    const int lq   = lane >> 4;
    const int bid  = blockIdx.x;
    const int mg   = bid >> 5;        // 0..3
    const int ug   = bid & 31;        // 0..31
    const int m0   = mg * 16;
    const int u0   = ug * 32;
    const int kc0  = wv * 128;

    // Whh slice as MFMA B-fragments, pinned for the whole scan.
    bf16x8 Bf[3][2][4];
#pragma unroll
    for (int g = 0; g < 3; ++g)
#pragma unroll
        for (int f = 0; f < 2; ++f)
#pragma unroll
            for (int ks = 0; ks < 4; ++ks)
                Bf[g][f][ks] = *(const bf16x8*)(Whh + (long)(g * NH + u0 + f * 16 + l16) * NH + kc0 + ks * 32 + lq * 8);
#pragma unroll
    for (int g = 0; g < 3; ++g)
#pragma unroll
        for (int f = 0; f < 2; ++f)
#pragma unroll
            for (int ks = 0; ks < 4; ++ks)
                asm volatile("" : "+v"(Bf[g][f][ks]));  // forbid rematerialization

    // epilogue ownership: 1 output (b_own, u_own) per thread
    const int u_loc = tid & 31;
    const int b_loc = tid >> 5;       // 0..15
    const int b_own = m0 + b_loc;
    const int u_own = u0 + u_loc;
    float bh[3];
#pragma unroll
    for (int g = 0; g < 3; ++g) bh[g] = bhh[g * NH + u_own];
    float hf = 0.0f;                  // fp32 h for (b_own,u_own), in-register

    // C-frag element holding (b_loc, u_loc&15)
    const int lane_t = (b_loc >> 2) * 16 + (u_loc & 15);
    const int i_t    = b_loc & 3;
    const int shalf  = (u_loc >> 4) * 3;   // frag-slot base: 0 or 3

    // this wave's 4 producer flags (K-chunk kc0..kc0+128 = ublocks wv*4..+3)
    const unsigned* fp_my = flags + mg * 32 + wv * 4 + (lane & 3);

    __shared__ f32x4 red[8][6][64];   // 48 KB

    for (int t = 0; t < NT; ++t) {
        const int slot_r = (t + 3) & 3;
        const int slot_w = t & 3;

        // xp loads for epilogue (plain cached; overlap with the poll)
        const unsigned short* xpp = xp + (((long)t * 32 + ug) * 64 + b_own) * 96;
        float xr = bf2f(xpp[u_loc]);
        float xz = bf2f(xpp[32 + u_loc]);
        float xn = bf2f(xpp[64 + u_loc]);

        // ---- per-wave poll: only THIS wave's 4 producers (4 UC dwords) ----
        if (t > 0) {
            for (;;) {
                unsigned fv;
                asm volatile("global_load_dword %0, %1, off sc0 sc1\n\ts_waitcnt vmcnt(0)"
                             : "=v"(fv) : "v"(fp_my) : "memory");
                if (__all(fv >= (unsigned)t)) break;
            }
        }

        // ---- h chunk load, exactly once: 4 x dwordx4 = 64B/lane ----
        const unsigned short* hp = hring + ((slot_r * NB + m0 + l16) * NH + kc0 + lq * 8);
        bf16x8 av[4];
        asm volatile(
            "global_load_dwordx4 %0, %4, off sc0 sc1\n\t"
            "global_load_dwordx4 %1, %4, off offset:64 sc0 sc1\n\t"
            "global_load_dwordx4 %2, %4, off offset:128 sc0 sc1\n\t"
            "global_load_dwordx4 %3, %4, off offset:192 sc0 sc1\n\t"
            "s_waitcnt vmcnt(0)"
            : "=&v"(av[0]), "=&v"(av[1]), "=&v"(av[2]), "=&v"(av[3])
            : "v"(hp) : "memory");

        f32x4 acc[2][3];
#pragma unroll
        for (int f = 0; f < 2; ++f)
#pragma unroll
            for (int g = 0; g < 3; ++g) acc[f][g] = (f32x4){0.f, 0.f, 0.f, 0.f};
#pragma unroll
        for (int ks = 0; ks < 4; ++ks)
#pragma unroll
            for (int f = 0; f < 2; ++f)
#pragma unroll
                for (int g = 0; g < 3; ++g)
                    acc[f][g] = mfma16(av[ks], Bf[g][f][ks], acc[f][g]);

#pragma unroll
        for (int f = 0; f < 2; ++f)
#pragma unroll
            for (int g = 0; g < 3; ++g) red[wv][f * 3 + g][lane] = acc[f][g];
        __syncthreads();  // all waves' partials in LDS (union of polls = 32 blocks >= t)

        float pre[3];
#pragma unroll
        for (int g = 0; g < 3; ++g) {
            float s = 0.0f;
#pragma unroll
            for (int w = 0; w < 8; ++w) s += red[w][shalf + g][lane_t][i_t];
            pre[g] = s + bh[g];
        }

        float r = 1.0f / (1.0f + __expf(-(xr + pre[0])));
        float z = 1.0f / (1.0f + __expf(-(xz + pre[1])));
        float narg = xn + r * pre[2];
        float nval = 1.0f - 2.0f / (__expf(2.0f * narg) + 1.0f);  // tanh
        float hnew = (1.0f - z) * nval + z * hf;
        hf = hnew;

        // h store (sc0 sc1) -> drain -> barrier (also guards red[]) -> flag
        {
            unsigned short* hw = hring + (slot_w * NB + b_own) * NH + u_own;
            unsigned hv = (unsigned)f2bf(hnew);
            asm volatile("global_store_short %0, %1, off sc0 sc1"
                         :: "v"(hw), "v"(hv) : "memory");
        }
        asm volatile("s_waitcnt vmcnt(0)" ::: "memory");  // h visible at coherent point
        __syncthreads();                                   // all waves drained + red[] free
        if (tid == 0) {
            unsigned fv = (unsigned)(t + 1);
            asm volatile("global_store_dword %0, %1, off sc0 sc1"
                         :: "v"(flags + mg * 32 + ug), "v"(fv) : "memory");
        }
        out[((long)b_own * NT + t) * NH + u_own] = hnew;
    }
}

extern "C" void kernel_launch(void* const* d_in, const int* in_sizes, int n_in,
                              void* d_out, int out_size, void* d_ws, size_t ws_size,
                              hipStream_t stream) {
    const float* enc = (const float*)d_in[0];
    const float* Wih = (const float*)d_in[1];
    const float* Whh = (const float*)d_in[2];
    const float* bih = (const float*)d_in[3];
    const float* bhh = (const float*)d_in[4];
    float* out = (float*)d_out;

    // workspace carve
    char* p = (char*)d_ws;
    unsigned short* enc_t = (unsigned short*)p; p += (size_t)NT * NB * NH * 2;   // 64 MB
    unsigned short* xp    = (unsigned short*)p; p += (size_t)NT * NB * NG * 2;   // 192 MB
    unsigned short* wih_b = (unsigned short*)p; p += (size_t)NG * NH * 2;        // 6 MB
    unsigned short* whh_b = (unsigned short*)p; p += (size_t)NG * NH * 2;        // 6 MB
    size_t need = (size_t)(p - (char*)d_ws);

    // sync region aliases dead enc_t: [hring 4*64*1024 bf16][flags 128 u32]
    unsigned short* hring = enc_t;
    unsigned* flags = (unsigned*)(hring + (size_t)4 * NB * NH);

    if (ws_size < need) {
        long n = (long)out_size;
        k_fill_sentinel<<<(int)((n + 255) / 256), 256, 0, stream>>>(out, n);
        return;
    }

    // Phase 0: conversions (one kernel)
    {
        long ne = (long)NB * NT * NH;  // 33554432, covers NG*NH too
        k_prep<<<(int)((ne + 255) / 256), 256, 0, stream>>>(enc, enc_t, Wih, wih_b, Whh, whh_b);
    }

    // Phase 1: x_proj GEMM (reads enc_t), XCD-swizzled 1D grid
    k_xproj<<<6144, 256, 0, stream>>>(enc_t, wih_b, bih, xp);

    // Phase 1.5: zero sync region (after enc_t is dead)
    k_init_sync<<<(SYNC_WORDS + 255) / 256, 256, 0, stream>>>((unsigned*)hring);

    // Phase 2: one persistent scan kernel
    k_scan<<<128, 512, 0, stream>>>(whh_b, bhh, xp, hring, flags, out);
}